// Round 4
// baseline (33824.945 us; speedup 1.0000x reference)
//
#include <hip/hip_runtime.h>

#define T_STEPS 64
#define BATCH   128
#define HID     1024
#define VOCAB   10000
#define VPAD    10240
#define NSPLIT  8
#define KCHUNK  256
#define TKK     32
#define NTILES  (KCHUNK / TKK)   // 8

typedef unsigned short ushort_t;
typedef __attribute__((ext_vector_type(8))) short bf16x8_t;
typedef __attribute__((ext_vector_type(4))) float f32x4_t;

__device__ inline unsigned short f2bf(float f) {
    unsigned int u = __float_as_uint(f);
    u += 0x7fffu + ((u >> 16) & 1u);
    return (unsigned short)(u >> 16);
}

// ---------------------------------------------------------------------------
// init / final copies
// ---------------------------------------------------------------------------
__global__ void init_h(const float* __restrict__ hidden,
                       float* __restrict__ h0, float* __restrict__ h1)
{
    int i = blockIdx.x * blockDim.x + threadIdx.x;
    if (i < BATCH * HID) {
        h0[i] = hidden[i];
        h1[i] = hidden[BATCH * HID + i];
    }
}

__global__ void final_h(const float* __restrict__ h0, const float* __restrict__ h1,
                        float* __restrict__ out)
{
    int i = blockIdx.x * blockDim.x + threadIdx.x;
    if (i < BATCH * HID) {
        out[i] = h0[i];
        out[BATCH * HID + i] = h1[i];
    }
}

// ---------------------------------------------------------------------------
// Embedding gather: xemb[row][k] = emb[ids[row]][k]
// ---------------------------------------------------------------------------
__global__ __launch_bounds__(256)
void gather_kernel(const int* __restrict__ ids, const float* __restrict__ emb,
                   float* __restrict__ xemb)
{
    const int row = blockIdx.x;
    const int c4 = threadIdx.x * 4;
    float4 v = *(const float4*)&emb[(size_t)ids[row] * HID + c4];
    *(float4*)&xemb[(size_t)row * HID + c4] = v;
}

// ---------------------------------------------------------------------------
// Wout transpose + bf16: WT[v][k] = bf16(Wout[k][v]); rows >= VOCAB zeroed
// ---------------------------------------------------------------------------
__global__ __launch_bounds__(256)
void woutT_kernel(const float* __restrict__ Wout, ushort_t* __restrict__ WT)
{
    __shared__ float ld[32][33];
    const int v0 = blockIdx.x * 32, k0 = blockIdx.y * 32;
    const int r = threadIdx.x >> 3;
    const int c4 = (threadIdx.x & 7) * 4;
    #pragma unroll
    for (int q = 0; q < 4; ++q) {
        int v = v0 + c4 + q;
        float val = 0.0f;
        if (v < VOCAB) val = Wout[(size_t)(k0 + r) * VOCAB + v];
        ld[c4 + q][r] = val;
    }
    __syncthreads();
    ushort4 o;
    o.x = f2bf(ld[r][c4 + 0]);
    o.y = f2bf(ld[r][c4 + 1]);
    o.z = f2bf(ld[r][c4 + 2]);
    o.w = f2bf(ld[r][c4 + 3]);
    *(ushort4*)&WT[(size_t)(v0 + r) * HID + k0 + c4] = o;
}

// ---------------------------------------------------------------------------
// agemm: rz partial GEMMs, split-K chunk 256 (8 splits), both layers.
//   A[b,k] (layer0) = k<H ? xemb_t0 : h0      A[b,k] (layer1) = k<H ? h0 : h1
//   B col j in [0,2048): j<H -> Wr else Wz
// TM=128, TN=64, TKK=32, double-buffered LDS, 4x8 per-thread tile.
// grid (32, 8, 2), 256 threads.  Accumulation order: k ascending (unchanged).
// ---------------------------------------------------------------------------
__global__ __launch_bounds__(256, 3)
void agemm_kernel(const float* __restrict__ xemb_t0,
                  const float* __restrict__ h0, const float* __restrict__ h1,
                  const float* __restrict__ Wr, const float* __restrict__ Wz,
                  float* __restrict__ part_rz, int do0, int do1)
{
    const int layer = blockIdx.z;
    if (layer == 0 && !do0) return;
    if (layer == 1 && !do1) return;

    __shared__ float As[2][128][33];
    __shared__ float Bs[2][32][68];
    const int tid = threadIdx.x;
    const int tx8 = (tid & 7) * 8;
    const int ty4 = (tid >> 3) * 4;
    const int j0 = blockIdx.x * 64;
    const int kbase = blockIdx.y * KCHUNK;

    const float* W = ((j0 < HID) ? Wr : Wz) + (size_t)layer * (2 * HID * HID);
    const int jc = j0 & (HID - 1);
    const float* A_lo = layer ? h0 : xemb_t0;
    const float* A_hi = layer ? h1 : h0;

    // per-thread staging coords
    int ar[4], ac[4];
    #pragma unroll
    for (int i = 0; i < 4; ++i) {
        int f = i * 256 + tid;
        ar[i] = f >> 3;             // 0..127
        ac[i] = (f & 7) * 4;        // 0..28
    }
    int br_[2], bc_[2];
    #pragma unroll
    for (int i = 0; i < 2; ++i) {
        int f = i * 256 + tid;
        br_[i] = f >> 4;            // 0..31
        bc_[i] = (f & 15) * 4;      // 0..60
    }

    float4 Areg[4], Breg[2];

    auto load_tile = [&](int t) {
        int kt = kbase + t * TKK;
        #pragma unroll
        for (int i = 0; i < 4; ++i) {
            int kg = kt + ac[i];
            const float* src = (kg < HID) ? A_lo : A_hi;
            Areg[i] = *(const float4*)&src[(size_t)ar[i] * HID + (kg & (HID - 1))];
        }
        #pragma unroll
        for (int i = 0; i < 2; ++i)
            Breg[i] = *(const float4*)&W[(size_t)(kt + br_[i]) * HID + jc + bc_[i]];
    };
    auto store_tile = [&](int buf) {
        #pragma unroll
        for (int i = 0; i < 4; ++i)
            *(float4*)&As[buf][ar[i]][ac[i]] = Areg[i];
        #pragma unroll
        for (int i = 0; i < 2; ++i)
            *(float4*)&Bs[buf][br_[i]][bc_[i]] = Breg[i];
    };

    float acc[4][8] = {};

    load_tile(0);
    store_tile(0);
    __syncthreads();

    for (int t = 0; t < NTILES; ++t) {
        if (t + 1 < NTILES) load_tile(t + 1);
        const int buf = t & 1;
        #pragma unroll
        for (int kk4 = 0; kk4 < TKK; kk4 += 4) {
            float4 a[4], b0[4], b1[4];
            #pragma unroll
            for (int i = 0; i < 4; ++i)
                a[i] = *(const float4*)&As[buf][ty4 + i][kk4];
            #pragma unroll
            for (int q = 0; q < 4; ++q) {
                b0[q] = *(const float4*)&Bs[buf][kk4 + q][tx8];
                b1[q] = *(const float4*)&Bs[buf][kk4 + q][tx8 + 4];
            }
            #pragma unroll
            for (int q = 0; q < 4; ++q) {
                #pragma unroll
                for (int i = 0; i < 4; ++i) {
                    acc[i][0] += a[i][q] * b0[q][0];
                    acc[i][1] += a[i][q] * b0[q][1];
                    acc[i][2] += a[i][q] * b0[q][2];
                    acc[i][3] += a[i][q] * b0[q][3];
                    acc[i][4] += a[i][q] * b1[q][0];
                    acc[i][5] += a[i][q] * b1[q][1];
                    acc[i][6] += a[i][q] * b1[q][2];
                    acc[i][7] += a[i][q] * b1[q][3];
                }
            }
        }
        __syncthreads();
        if (t + 1 < NTILES) {
            store_tile((t + 1) & 1);
            __syncthreads();
        }
    }

    float* dst = part_rz + (size_t)(layer * NSPLIT + blockIdx.y) * (BATCH * 2 * HID);
    #pragma unroll
    for (int i = 0; i < 4; ++i) {
        int b = ty4 + i;
        float4 v0, v1;
        v0.x = acc[i][0]; v0.y = acc[i][1]; v0.z = acc[i][2]; v0.w = acc[i][3];
        v1.x = acc[i][4]; v1.y = acc[i][5]; v1.z = acc[i][6]; v1.w = acc[i][7];
        *(float4*)&dst[(size_t)b * 2048 + j0 + tx8]     = v0;
        *(float4*)&dst[(size_t)b * 2048 + j0 + tx8 + 4] = v1;
    }
}

// ---------------------------------------------------------------------------
// aact: r = tanh(sum_splits part_rz[.., j<H] + br)   (unchanged numerics)
// ---------------------------------------------------------------------------
__global__ __launch_bounds__(256)
void aact_kernel(const float* __restrict__ part_rz,
                 const float* __restrict__ br,
                 float* __restrict__ rmat0, float* __restrict__ rmat1,
                 int do0, int do1)
{
    const int layer = blockIdx.y;
    if (layer == 0 && !do0) return;
    if (layer == 1 && !do1) return;
    const int idx4 = (blockIdx.x * 256 + threadIdx.x) * 4;
    const int b = idx4 >> 10, j = idx4 & (HID - 1);
    const float* p = part_rz + (size_t)layer * NSPLIT * (BATCH * 2 * HID)
                   + (size_t)b * 2048 + j;
    float4 s = {0.f, 0.f, 0.f, 0.f};
    #pragma unroll
    for (int sp = 0; sp < NSPLIT; ++sp) {
        float4 v = *(const float4*)&p[(size_t)sp * (BATCH * 2 * HID)];
        s.x += v.x; s.y += v.y; s.z += v.z; s.w += v.w;
    }
    float4 bb = *(const float4*)&br[layer * HID + j];
    float4 r;
    r.x = tanhf(s.x + bb.x); r.y = tanhf(s.y + bb.y);
    r.z = tanhf(s.z + bb.z); r.w = tanhf(s.w + bb.w);
    *(float4*)&(layer ? rmat1 : rmat0)[idx4] = r;
}

// ---------------------------------------------------------------------------
// bgemm: g partial GEMMs, split-K chunk 256 (8 splits), both layers. K=2048.
//   A2[b,k] (layer0) = k<H ? xemb_t0 : r0*h0
//   A2[b,k] (layer1) = k<H ? h0      : r1*h1
// TM=128, TN=32, TKK=32, double-buffered, 4x4 per-thread tile.
// grid (32, 8, 2), 256 threads.
// ---------------------------------------------------------------------------
__global__ __launch_bounds__(256, 3)
void bgemm_kernel(const float* __restrict__ xemb_t0,
                  const float* __restrict__ h0, const float* __restrict__ h1,
                  const float* __restrict__ rmat0, const float* __restrict__ rmat1,
                  const float* __restrict__ Wg,
                  float* __restrict__ part_g, int do0, int do1)
{
    const int layer = blockIdx.z;
    if (layer == 0 && !do0) return;
    if (layer == 1 && !do1) return;

    __shared__ float As[2][128][33];
    __shared__ float Bs[2][32][36];
    const int tid = threadIdx.x;
    const int tx4 = (tid & 7) * 4;
    const int ty4 = (tid >> 3) * 4;
    const int j0 = blockIdx.x * 32;
    const int kbase = blockIdx.y * KCHUNK;

    const float* W = Wg + (size_t)layer * (2 * HID * HID);
    const float* A_lo = layer ? h0 : xemb_t0;
    const float* A_hi = layer ? h1 : h0;
    const float* R    = layer ? rmat1 : rmat0;

    int ar[4], ac[4];
    #pragma unroll
    for (int i = 0; i < 4; ++i) {
        int f = i * 256 + tid;
        ar[i] = f >> 3;
        ac[i] = (f & 7) * 4;
    }
    const int bkr = tid >> 3;           // 0..31
    const int bcc = (tid & 7) * 4;      // 0..28

    float4 Areg[4], Breg;

    auto load_tile = [&](int t) {
        int kt = kbase + t * TKK;
        #pragma unroll
        for (int i = 0; i < 4; ++i) {
            int kg = kt + ac[i];
            int km = kg & (HID - 1);
            if (kg < HID) {
                Areg[i] = *(const float4*)&A_lo[(size_t)ar[i] * HID + km];
            } else {
                float4 rv = *(const float4*)&R[(size_t)ar[i] * HID + km];
                float4 hv = *(const float4*)&A_hi[(size_t)ar[i] * HID + km];
                Areg[i].x = rv.x * hv.x; Areg[i].y = rv.y * hv.y;
                Areg[i].z = rv.z * hv.z; Areg[i].w = rv.w * hv.w;
            }
        }
        Breg = *(const float4*)&W[(size_t)(kt + bkr) * HID + j0 + bcc];
    };
    auto store_tile = [&](int buf) {
        #pragma unroll
        for (int i = 0; i < 4; ++i)
            *(float4*)&As[buf][ar[i]][ac[i]] = Areg[i];
        *(float4*)&Bs[buf][bkr][bcc] = Breg;
    };

    float acc[4][4] = {};

    load_tile(0);
    store_tile(0);
    __syncthreads();

    for (int t = 0; t < NTILES; ++t) {
        if (t + 1 < NTILES) load_tile(t + 1);
        const int buf = t & 1;
        #pragma unroll
        for (int kk4 = 0; kk4 < TKK; kk4 += 4) {
            float4 a[4], b[4];
            #pragma unroll
            for (int i = 0; i < 4; ++i)
                a[i] = *(const float4*)&As[buf][ty4 + i][kk4];
            #pragma unroll
            for (int q = 0; q < 4; ++q)
                b[q] = *(const float4*)&Bs[buf][kk4 + q][tx4];
            #pragma unroll
            for (int q = 0; q < 4; ++q) {
                #pragma unroll
                for (int i = 0; i < 4; ++i) {
                    acc[i][0] += a[i][q] * b[q].x;
                    acc[i][1] += a[i][q] * b[q].y;
                    acc[i][2] += a[i][q] * b[q].z;
                    acc[i][3] += a[i][q] * b[q].w;
                }
            }
        }
        __syncthreads();
        if (t + 1 < NTILES) {
            store_tile((t + 1) & 1);
            __syncthreads();
        }
    }

    float* dst = part_g + (size_t)(layer * NSPLIT + blockIdx.y) * (BATCH * HID);
    #pragma unroll
    for (int i = 0; i < 4; ++i) {
        int b = ty4 + i;
        float4 v;
        v.x = acc[i][0]; v.y = acc[i][1]; v.z = acc[i][2]; v.w = acc[i][3];
        *(float4*)&dst[(size_t)b * HID + j0 + tx4] = v;
    }
}

// ---------------------------------------------------------------------------
// bact: z/g reduction + tanh + h update (unchanged numerics)
// ---------------------------------------------------------------------------
__global__ __launch_bounds__(256)
void bact_kernel(const float* __restrict__ part_rz, const float* __restrict__ part_g,
                 const float* __restrict__ bz, const float* __restrict__ bg,
                 float* __restrict__ h0, float* __restrict__ h1,
                 ushort_t* __restrict__ h1bf, int t1, int do0, int do1)
{
    const int layer = blockIdx.y;
    if (layer == 0 && !do0) return;
    if (layer == 1 && !do1) return;
    const int idx4 = (blockIdx.x * 256 + threadIdx.x) * 4;
    const int b = idx4 >> 10, j = idx4 & (HID - 1);

    const float* pz = part_rz + (size_t)layer * NSPLIT * (BATCH * 2 * HID)
                    + (size_t)b * 2048 + HID + j;
    float4 sz = {0.f, 0.f, 0.f, 0.f};
    #pragma unroll
    for (int sp = 0; sp < NSPLIT; ++sp) {
        float4 v = *(const float4*)&pz[(size_t)sp * (BATCH * 2 * HID)];
        sz.x += v.x; sz.y += v.y; sz.z += v.z; sz.w += v.w;
    }
    float4 bzv = *(const float4*)&bz[layer * HID + j];
    float4 z;
    z.x = tanhf(sz.x + bzv.x); z.y = tanhf(sz.y + bzv.y);
    z.z = tanhf(sz.z + bzv.z); z.w = tanhf(sz.w + bzv.w);

    const float* pg = part_g + (size_t)layer * NSPLIT * (BATCH * HID) + idx4;
    float4 sg = {0.f, 0.f, 0.f, 0.f};
    #pragma unroll
    for (int sp = 0; sp < NSPLIT; ++sp) {
        float4 v = *(const float4*)&pg[(size_t)sp * (BATCH * HID)];
        sg.x += v.x; sg.y += v.y; sg.z += v.z; sg.w += v.w;
    }
    float4 bgv = *(const float4*)&bg[layer * HID + j];
    float4 g;
    g.x = tanhf(sg.x + bgv.x); g.y = tanhf(sg.y + bgv.y);
    g.z = tanhf(sg.z + bgv.z); g.w = tanhf(sg.w + bgv.w);

    float* h = layer ? h1 : h0;
    float4 hv = *(const float4*)&h[idx4];
    float4 hn;
    hn.x = (1.0f - z.x) * hv.x + z.x * g.x;
    hn.y = (1.0f - z.y) * hv.y + z.y * g.y;
    hn.z = (1.0f - z.z) * hv.z + z.z * g.z;
    hn.w = (1.0f - z.w) * hv.w + z.w * g.w;
    *(float4*)&h[idx4] = hn;

    if (layer == 1) {
        ushort4 o;
        o.x = f2bf(hn.x); o.y = f2bf(hn.y); o.z = f2bf(hn.z); o.w = f2bf(hn.w);
        *(ushort4*)&h1bf[(size_t)t1 * (BATCH * HID) + idx4] = o;
    }
}

// ---------------------------------------------------------------------------
// Logits MFMA GEMM (unchanged): out[i,v] = tanh(h1bf[i,:] @ WT[v,:] + bout[v])
// ---------------------------------------------------------------------------
typedef const unsigned int __attribute__((address_space(1)))* gptr1_t;
typedef unsigned int __attribute__((address_space(3)))* lptr3_t;

__global__ __launch_bounds__(256)
void logits_mfma_kernel(const ushort_t* __restrict__ Abf,
                        const ushort_t* __restrict__ BT,
                        const float* __restrict__ bout,
                        float* __restrict__ out)
{
    __shared__ ushort_t As[128 * 64];
    __shared__ ushort_t Bs[128 * 64];
    const int tid = threadIdx.x;
    const int wave = tid >> 6, lane = tid & 63;
    const int m0 = blockIdx.y * 128, n0 = blockIdx.x * 128;
    const int wr = wave >> 1, wc = wave & 1;

    const int srow = lane >> 3;
    const int sch = (lane & 7) ^ (srow & 7);
    const int lrow = lane & 15, lhi = lane >> 4;

    f32x4_t acc[4][4] = {};

    for (int k0 = 0; k0 < HID; k0 += 64) {
        #pragma unroll
        for (int i = 0; i < 4; ++i) {
            int issue = wave * 4 + i;
            int row = issue * 8 + srow;
            const ushort_t* ga = Abf + (size_t)(m0 + row) * HID + k0 + sch * 8;
            const ushort_t* gb = BT + (size_t)(n0 + row) * HID + k0 + sch * 8;
#if defined(__has_builtin) && __has_builtin(__builtin_amdgcn_global_load_lds)
            __builtin_amdgcn_global_load_lds((gptr1_t)(const void*)ga,
                                             (lptr3_t)(void*)(As + issue * 512), 16, 0, 0);
            __builtin_amdgcn_global_load_lds((gptr1_t)(const void*)gb,
                                             (lptr3_t)(void*)(Bs + issue * 512), 16, 0, 0);
#else
            *(bf16x8_t*)(As + issue * 512 + lane * 8) = *(const bf16x8_t*)ga;
            *(bf16x8_t*)(Bs + issue * 512 + lane * 8) = *(const bf16x8_t*)gb;
#endif
        }
        __syncthreads();

        bf16x8_t af[4][2], bfm[4][2];
        const char* Ab = (const char*)As;
        const char* Bb = (const char*)Bs;
        #pragma unroll
        for (int m = 0; m < 4; ++m) {
            int row = wr * 64 + m * 16 + lrow;
            #pragma unroll
            for (int ks = 0; ks < 2; ++ks) {
                int off = row * 128 + (((ks * 4 + lhi) ^ (lrow & 7)) * 16);
                af[m][ks] = *(const bf16x8_t*)(Ab + off);
            }
        }
        #pragma unroll
        for (int n = 0; n < 4; ++n) {
            int row = wc * 64 + n * 16 + lrow;
            #pragma unroll
            for (int ks = 0; ks < 2; ++ks) {
                int off = row * 128 + (((ks * 4 + lhi) ^ (lrow & 7)) * 16);
                bfm[n][ks] = *(const bf16x8_t*)(Bb + off);
            }
        }
        #pragma unroll
        for (int m = 0; m < 4; ++m)
            #pragma unroll
            for (int n = 0; n < 4; ++n)
                #pragma unroll
                for (int ks = 0; ks < 2; ++ks)
                    acc[m][n] = __builtin_amdgcn_mfma_f32_16x16x32_bf16(
                        af[m][ks], bfm[n][ks], acc[m][n], 0, 0, 0);
        __syncthreads();
    }

    #pragma unroll
    for (int m = 0; m < 4; ++m) {
        int row = m0 + wr * 64 + m * 16 + lhi * 4;
        #pragma unroll
        for (int n = 0; n < 4; ++n) {
            int col = n0 + wc * 64 + n * 16 + lrow;
            if (col < VOCAB) {
                float bo = bout[col];
                #pragma unroll
                for (int q = 0; q < 4; ++q)
                    out[(size_t)(row + q) * VOCAB + col] = tanhf(acc[m][n][q] + bo);
            }
        }
    }
}

// ---------------------------------------------------------------------------
extern "C" void kernel_launch(void* const* d_in, const int* in_sizes, int n_in,
                              void* d_out, int out_size, void* d_ws, size_t ws_size,
                              hipStream_t stream)
{
    const int*   inputs = (const int*)  d_in[0];
    const float* hidden = (const float*)d_in[1];
    const float* emb    = (const float*)d_in[2];
    const float* Wr     = (const float*)d_in[3];
    const float* br     = (const float*)d_in[4];
    const float* Wz     = (const float*)d_in[5];
    const float* bz     = (const float*)d_in[6];
    const float* Wg     = (const float*)d_in[7];
    const float* bg     = (const float*)d_in[8];
    const float* Wout   = (const float*)d_in[9];
    const float* bout   = (const float*)d_in[10];
    float* out = (float*)d_out;

    const size_t BH = BATCH * HID;                 // 131072

    float* ws = (float*)d_ws;
    float* h0      = ws;                           // BH
    float* h1      = h0 + BH;                      // BH
    float* rmat0   = h1 + BH;                      // BH
    float* rmat1   = rmat0 + BH;                   // BH
    float* part_rz = rmat1 + BH;                   // 2*8*262144
    float* part_g  = part_rz + 2 * NSPLIT * (BATCH * 2 * HID);  // 2*8*131072
    float* xemb    = part_g + 2 * NSPLIT * (BATCH * HID);       // T*B*H
    ushort_t* h1bf = (ushort_t*)(xemb + (size_t)T_STEPS * BH);  // T*B*H bf16
    ushort_t* WT   = h1bf + (size_t)T_STEPS * BH;               // VPAD*H bf16

    init_h<<<(int)(BH + 255) / 256, 256, 0, stream>>>(hidden, h0, h1);
    gather_kernel<<<T_STEPS * BATCH, 256, 0, stream>>>(inputs, emb, xemb);
    woutT_kernel<<<dim3(VPAD / 32, HID / 32), 256, 0, stream>>>(Wout, WT);

    for (int s = 0; s <= T_STEPS; ++s) {
        int do0 = (s < T_STEPS) ? 1 : 0;
        int do1 = (s >= 1) ? 1 : 0;
        const float* xemb_t0 = xemb + (size_t)s * BH;
        agemm_kernel<<<dim3(32, NSPLIT, 2), 256, 0, stream>>>(
            xemb_t0, h0, h1, Wr, Wz, part_rz, do0, do1);
        aact_kernel<<<dim3(128, 2), 256, 0, stream>>>(
            part_rz, br, rmat0, rmat1, do0, do1);
        bgemm_kernel<<<dim3(32, NSPLIT, 2), 256, 0, stream>>>(
            xemb_t0, h0, h1, rmat0, rmat1, Wg, part_g, do0, do1);
        bact_kernel<<<dim3(128, 2), 256, 0, stream>>>(
            part_rz, part_g, bz, bg, h0, h1, h1bf, s - 1, do0, do1);
    }

    final_h<<<(int)(BH + 255) / 256, 256, 0, stream>>>(
        h0, h1, out + (size_t)T_STEPS * BATCH * VOCAB);

    logits_mfma_kernel<<<dim3(VPAD / 128, 8192 / 128), 256, 0, stream>>>(
        h1bf, WT, bout, out);
}

// Round 5
// 4643.035 us; speedup vs baseline: 7.2851x; 7.2851x over previous
//
#include <hip/hip_runtime.h>

#define T_STEPS 64
#define BATCH   128
#define HID     1024
#define VOCAB   10000
#define VPAD    10240
#define NSPLIT  8
#define KCHUNK  256

typedef unsigned short ushort_t;
typedef __attribute__((ext_vector_type(8))) short bf16x8_t;
typedef __attribute__((ext_vector_type(4))) float f32x4_t;

__device__ inline unsigned short f2bf(float f) {
    unsigned int u = __float_as_uint(f);
    u += 0x7fffu + ((u >> 16) & 1u);
    return (unsigned short)(u >> 16);
}

// ---------------------------------------------------------------------------
// init / final copies
// ---------------------------------------------------------------------------
__global__ void init_h(const float* __restrict__ hidden,
                       float* __restrict__ h0, float* __restrict__ h1)
{
    int i = blockIdx.x * blockDim.x + threadIdx.x;
    if (i < BATCH * HID) {
        h0[i] = hidden[i];
        h1[i] = hidden[BATCH * HID + i];
    }
}

__global__ void final_h(const float* __restrict__ h0, const float* __restrict__ h1,
                        float* __restrict__ out)
{
    int i = blockIdx.x * blockDim.x + threadIdx.x;
    if (i < BATCH * HID) {
        out[i] = h0[i];
        out[BATCH * HID + i] = h1[i];
    }
}

// ---------------------------------------------------------------------------
// Embedding gather: xemb[row][k] = emb[ids[row]][k]
// ---------------------------------------------------------------------------
__global__ __launch_bounds__(256)
void gather_kernel(const int* __restrict__ ids, const float* __restrict__ emb,
                   float* __restrict__ xemb)
{
    const int row = blockIdx.x;
    const int c4 = threadIdx.x * 4;
    float4 v = *(const float4*)&emb[(size_t)ids[row] * HID + c4];
    *(float4*)&xemb[(size_t)row * HID + c4] = v;
}

// ---------------------------------------------------------------------------
// Wout transpose + bf16: WT[v][k] = bf16(Wout[k][v]); rows >= VOCAB zeroed
// ---------------------------------------------------------------------------
__global__ __launch_bounds__(256)
void woutT_kernel(const float* __restrict__ Wout, ushort_t* __restrict__ WT)
{
    __shared__ float ld[32][33];
    const int v0 = blockIdx.x * 32, k0 = blockIdx.y * 32;
    const int r = threadIdx.x >> 3;
    const int c4 = (threadIdx.x & 7) * 4;
    #pragma unroll
    for (int q = 0; q < 4; ++q) {
        int v = v0 + c4 + q;
        float val = 0.0f;
        if (v < VOCAB) val = Wout[(size_t)(k0 + r) * VOCAB + v];
        ld[c4 + q][r] = val;
    }
    __syncthreads();
    ushort4 o;
    o.x = f2bf(ld[r][c4 + 0]);
    o.y = f2bf(ld[r][c4 + 1]);
    o.z = f2bf(ld[r][c4 + 2]);
    o.w = f2bf(ld[r][c4 + 3]);
    *(ushort4*)&WT[(size_t)(v0 + r) * HID + k0 + c4] = o;
}

// ---------------------------------------------------------------------------
// agemm: rz partial GEMMs, split-K chunk 256 (8 splits), both layers. K=2048.
//   A[b,k] (layer0) = k<H ? xemb_t0 : h0      A[b,k] (layer1) = k<H ? h0 : h1
//   B col j in [0,2048): j<H -> Wr else Wz
// TM=128, TN=64, TK=64, single-buffered, row-major A LDS, 4x8 per-thread tile.
// Thread rows: {ty, ty+32, ty+64, ty+96} (bank-conflict-free A reads).
// grid (32, 8, 2), 256 threads. Per-element accumulation: k ascending.
// ---------------------------------------------------------------------------
__global__ __launch_bounds__(256)
void agemm_kernel(const float* __restrict__ xemb_t0,
                  const float* __restrict__ h0, const float* __restrict__ h1,
                  const float* __restrict__ Wr, const float* __restrict__ Wz,
                  float* __restrict__ part_rz, int do0, int do1)
{
    const int layer = blockIdx.z;
    if (layer == 0 && !do0) return;
    if (layer == 1 && !do1) return;

    __shared__ float As[128][68];
    __shared__ float Bs[64][68];
    const int tid = threadIdx.x;
    const int tx8 = (tid & 7) * 8;      // 0..56
    const int ty  = tid >> 3;           // 0..31
    const int j0 = blockIdx.x * 64;
    const int kbase = blockIdx.y * KCHUNK;

    const float* W = ((j0 < HID) ? Wr : Wz) + (size_t)layer * (2 * HID * HID);
    const int jc = j0 & (HID - 1);
    const float* A_lo = layer ? h0 : xemb_t0;
    const float* A_hi = layer ? h1 : h0;

    float acc[4][8] = {};

    for (int kt0 = 0; kt0 < KCHUNK; kt0 += 64) {
        const int kt = kbase + kt0;
        // stage A row-major: 128 rows x 64 k, 8 x ds_write_b128 per thread
        #pragma unroll
        for (int i = 0; i < 8; ++i) {
            int f = i * 256 + tid;
            int r = f >> 4;             // 0..127
            int c4 = (f & 15) * 4;      // 0..60
            int kg = kt + c4;
            const float* src = (kg < HID) ? A_lo : A_hi;
            *(float4*)&As[r][c4] =
                *(const float4*)&src[(size_t)r * HID + (kg & (HID - 1))];
        }
        // stage B: 64 rows(k) x 64 cols(j), 4 x ds_write_b128 per thread
        #pragma unroll
        for (int i = 0; i < 4; ++i) {
            int f = i * 256 + tid;
            int r = f >> 4;             // 0..63
            int c4 = (f & 15) * 4;      // 0..60
            *(float4*)&Bs[r][c4] =
                *(const float4*)&W[(size_t)(kt + r) * HID + jc + c4];
        }
        __syncthreads();
        #pragma unroll
        for (int kk4 = 0; kk4 < 64; kk4 += 4) {
            float4 a[4], b0[4], b1[4];
            #pragma unroll
            for (int i = 0; i < 4; ++i)
                a[i] = *(const float4*)&As[ty + i * 32][kk4];
            #pragma unroll
            for (int q = 0; q < 4; ++q) {
                b0[q] = *(const float4*)&Bs[kk4 + q][tx8];
                b1[q] = *(const float4*)&Bs[kk4 + q][tx8 + 4];
            }
            #pragma unroll
            for (int q = 0; q < 4; ++q) {
                #pragma unroll
                for (int i = 0; i < 4; ++i) {
                    acc[i][0] += a[i][q] * b0[q][0];
                    acc[i][1] += a[i][q] * b0[q][1];
                    acc[i][2] += a[i][q] * b0[q][2];
                    acc[i][3] += a[i][q] * b0[q][3];
                    acc[i][4] += a[i][q] * b1[q][0];
                    acc[i][5] += a[i][q] * b1[q][1];
                    acc[i][6] += a[i][q] * b1[q][2];
                    acc[i][7] += a[i][q] * b1[q][3];
                }
            }
        }
        __syncthreads();
    }

    float* dst = part_rz + (size_t)(layer * NSPLIT + blockIdx.y) * (BATCH * 2 * HID);
    #pragma unroll
    for (int i = 0; i < 4; ++i) {
        int b = ty + i * 32;
        float4 v0, v1;
        v0.x = acc[i][0]; v0.y = acc[i][1]; v0.z = acc[i][2]; v0.w = acc[i][3];
        v1.x = acc[i][4]; v1.y = acc[i][5]; v1.z = acc[i][6]; v1.w = acc[i][7];
        *(float4*)&dst[(size_t)b * 2048 + j0 + tx8]     = v0;
        *(float4*)&dst[(size_t)b * 2048 + j0 + tx8 + 4] = v1;
    }
}

// ---------------------------------------------------------------------------
// aact: r = tanh(sum_splits part_rz[.., j<H] + br)   (unchanged)
// ---------------------------------------------------------------------------
__global__ __launch_bounds__(256)
void aact_kernel(const float* __restrict__ part_rz,
                 const float* __restrict__ br,
                 float* __restrict__ rmat0, float* __restrict__ rmat1,
                 int do0, int do1)
{
    const int layer = blockIdx.y;
    if (layer == 0 && !do0) return;
    if (layer == 1 && !do1) return;
    const int idx4 = (blockIdx.x * 256 + threadIdx.x) * 4;
    const int b = idx4 >> 10, j = idx4 & (HID - 1);
    const float* p = part_rz + (size_t)layer * NSPLIT * (BATCH * 2 * HID)
                   + (size_t)b * 2048 + j;
    float4 s = {0.f, 0.f, 0.f, 0.f};
    #pragma unroll
    for (int sp = 0; sp < NSPLIT; ++sp) {
        float4 v = *(const float4*)&p[(size_t)sp * (BATCH * 2 * HID)];
        s.x += v.x; s.y += v.y; s.z += v.z; s.w += v.w;
    }
    float4 bb = *(const float4*)&br[layer * HID + j];
    float4 r;
    r.x = tanhf(s.x + bb.x); r.y = tanhf(s.y + bb.y);
    r.z = tanhf(s.z + bb.z); r.w = tanhf(s.w + bb.w);
    *(float4*)&(layer ? rmat1 : rmat0)[idx4] = r;
}

// ---------------------------------------------------------------------------
// bgemm: g partial GEMMs, split-K chunk 256 (8 splits), both layers. K=2048.
//   A2[b,k] (layer0) = k<H ? xemb_t0 : r0*h0
//   A2[b,k] (layer1) = k<H ? h0      : r1*h1
// TM=128, TN=32, TK=64, single-buffered, row-major A LDS, 4x4 per-thread tile.
// grid (32, 8, 2), 256 threads.
// ---------------------------------------------------------------------------
__global__ __launch_bounds__(256)
void bgemm_kernel(const float* __restrict__ xemb_t0,
                  const float* __restrict__ h0, const float* __restrict__ h1,
                  const float* __restrict__ rmat0, const float* __restrict__ rmat1,
                  const float* __restrict__ Wg,
                  float* __restrict__ part_g, int do0, int do1)
{
    const int layer = blockIdx.z;
    if (layer == 0 && !do0) return;
    if (layer == 1 && !do1) return;

    __shared__ float As[128][68];
    __shared__ float Bs[64][36];
    const int tid = threadIdx.x;
    const int tx4 = (tid & 7) * 4;      // 0..28
    const int ty  = tid >> 3;           // 0..31
    const int j0 = blockIdx.x * 32;
    const int kbase = blockIdx.y * KCHUNK;

    const float* W = Wg + (size_t)layer * (2 * HID * HID);
    const float* A_lo = layer ? h0 : xemb_t0;
    const float* A_hi = layer ? h1 : h0;
    const float* R    = layer ? rmat1 : rmat0;

    float acc[4][4] = {};

    for (int kt0 = 0; kt0 < KCHUNK; kt0 += 64) {
        const int kt = kbase + kt0;
        // stage A row-major: gate-multiplied upper half
        #pragma unroll
        for (int i = 0; i < 8; ++i) {
            int f = i * 256 + tid;
            int r = f >> 4;
            int c4 = (f & 15) * 4;
            int kg = kt + c4;
            int km = kg & (HID - 1);
            float4 v;
            if (kg < HID) {
                v = *(const float4*)&A_lo[(size_t)r * HID + km];
            } else {
                float4 rv = *(const float4*)&R[(size_t)r * HID + km];
                float4 hv = *(const float4*)&A_hi[(size_t)r * HID + km];
                v.x = rv.x * hv.x; v.y = rv.y * hv.y;
                v.z = rv.z * hv.z; v.w = rv.w * hv.w;
            }
            *(float4*)&As[r][c4] = v;
        }
        // stage B: 64 rows(k) x 32 cols(j), 2 x ds_write_b128 per thread
        #pragma unroll
        for (int i = 0; i < 2; ++i) {
            int f = i * 256 + tid;
            int r = f >> 3;             // 0..63
            int c4 = (f & 7) * 4;       // 0..28
            *(float4*)&Bs[r][c4] =
                *(const float4*)&W[(size_t)(kt + r) * HID + j0 + c4];
        }
        __syncthreads();
        #pragma unroll
        for (int kk4 = 0; kk4 < 64; kk4 += 4) {
            float4 a[4], b[4];
            #pragma unroll
            for (int i = 0; i < 4; ++i)
                a[i] = *(const float4*)&As[ty + i * 32][kk4];
            #pragma unroll
            for (int q = 0; q < 4; ++q)
                b[q] = *(const float4*)&Bs[kk4 + q][tx4];
            #pragma unroll
            for (int q = 0; q < 4; ++q) {
                #pragma unroll
                for (int i = 0; i < 4; ++i) {
                    acc[i][0] += a[i][q] * b[q].x;
                    acc[i][1] += a[i][q] * b[q].y;
                    acc[i][2] += a[i][q] * b[q].z;
                    acc[i][3] += a[i][q] * b[q].w;
                }
            }
        }
        __syncthreads();
    }

    float* dst = part_g + (size_t)(layer * NSPLIT + blockIdx.y) * (BATCH * HID);
    #pragma unroll
    for (int i = 0; i < 4; ++i) {
        int b = ty + i * 32;
        float4 v;
        v.x = acc[i][0]; v.y = acc[i][1]; v.z = acc[i][2]; v.w = acc[i][3];
        *(float4*)&dst[(size_t)b * HID + j0 + tx4] = v;
    }
}

// ---------------------------------------------------------------------------
// bact: z/g reduction + tanh + h update (unchanged)
// ---------------------------------------------------------------------------
__global__ __launch_bounds__(256)
void bact_kernel(const float* __restrict__ part_rz, const float* __restrict__ part_g,
                 const float* __restrict__ bz, const float* __restrict__ bg,
                 float* __restrict__ h0, float* __restrict__ h1,
                 ushort_t* __restrict__ h1bf, int t1, int do0, int do1)
{
    const int layer = blockIdx.y;
    if (layer == 0 && !do0) return;
    if (layer == 1 && !do1) return;
    const int idx4 = (blockIdx.x * 256 + threadIdx.x) * 4;
    const int b = idx4 >> 10, j = idx4 & (HID - 1);

    const float* pz = part_rz + (size_t)layer * NSPLIT * (BATCH * 2 * HID)
                    + (size_t)b * 2048 + HID + j;
    float4 sz = {0.f, 0.f, 0.f, 0.f};
    #pragma unroll
    for (int sp = 0; sp < NSPLIT; ++sp) {
        float4 v = *(const float4*)&pz[(size_t)sp * (BATCH * 2 * HID)];
        sz.x += v.x; sz.y += v.y; sz.z += v.z; sz.w += v.w;
    }
    float4 bzv = *(const float4*)&bz[layer * HID + j];
    float4 z;
    z.x = tanhf(sz.x + bzv.x); z.y = tanhf(sz.y + bzv.y);
    z.z = tanhf(sz.z + bzv.z); z.w = tanhf(sz.w + bzv.w);

    const float* pg = part_g + (size_t)layer * NSPLIT * (BATCH * HID) + idx4;
    float4 sg = {0.f, 0.f, 0.f, 0.f};
    #pragma unroll
    for (int sp = 0; sp < NSPLIT; ++sp) {
        float4 v = *(const float4*)&pg[(size_t)sp * (BATCH * HID)];
        sg.x += v.x; sg.y += v.y; sg.z += v.z; sg.w += v.w;
    }
    float4 bgv = *(const float4*)&bg[layer * HID + j];
    float4 g;
    g.x = tanhf(sg.x + bgv.x); g.y = tanhf(sg.y + bgv.y);
    g.z = tanhf(sg.z + bgv.z); g.w = tanhf(sg.w + bgv.w);

    float* h = layer ? h1 : h0;
    float4 hv = *(const float4*)&h[idx4];
    float4 hn;
    hn.x = (1.0f - z.x) * hv.x + z.x * g.x;
    hn.y = (1.0f - z.y) * hv.y + z.y * g.y;
    hn.z = (1.0f - z.z) * hv.z + z.z * g.z;
    hn.w = (1.0f - z.w) * hv.w + z.w * g.w;
    *(float4*)&h[idx4] = hn;

    if (layer == 1) {
        ushort4 o;
        o.x = f2bf(hn.x); o.y = f2bf(hn.y); o.z = f2bf(hn.z); o.w = f2bf(hn.w);
        *(ushort4*)&h1bf[(size_t)t1 * (BATCH * HID) + idx4] = o;
    }
}

// ---------------------------------------------------------------------------
// Logits MFMA GEMM (unchanged): out[i,v] = tanh(h1bf[i,:] @ WT[v,:] + bout[v])
// ---------------------------------------------------------------------------
typedef const unsigned int __attribute__((address_space(1)))* gptr1_t;
typedef unsigned int __attribute__((address_space(3)))* lptr3_t;

__global__ __launch_bounds__(256)
void logits_mfma_kernel(const ushort_t* __restrict__ Abf,
                        const ushort_t* __restrict__ BT,
                        const float* __restrict__ bout,
                        float* __restrict__ out)
{
    __shared__ ushort_t As[128 * 64];
    __shared__ ushort_t Bs[128 * 64];
    const int tid = threadIdx.x;
    const int wave = tid >> 6, lane = tid & 63;
    const int m0 = blockIdx.y * 128, n0 = blockIdx.x * 128;
    const int wr = wave >> 1, wc = wave & 1;

    const int srow = lane >> 3;
    const int sch = (lane & 7) ^ (srow & 7);
    const int lrow = lane & 15, lhi = lane >> 4;

    f32x4_t acc[4][4] = {};

    for (int k0 = 0; k0 < HID; k0 += 64) {
        #pragma unroll
        for (int i = 0; i < 4; ++i) {
            int issue = wave * 4 + i;
            int row = issue * 8 + srow;
            const ushort_t* ga = Abf + (size_t)(m0 + row) * HID + k0 + sch * 8;
            const ushort_t* gb = BT + (size_t)(n0 + row) * HID + k0 + sch * 8;
#if defined(__has_builtin) && __has_builtin(__builtin_amdgcn_global_load_lds)
            __builtin_amdgcn_global_load_lds((gptr1_t)(const void*)ga,
                                             (lptr3_t)(void*)(As + issue * 512), 16, 0, 0);
            __builtin_amdgcn_global_load_lds((gptr1_t)(const void*)gb,
                                             (lptr3_t)(void*)(Bs + issue * 512), 16, 0, 0);
#else
            *(bf16x8_t*)(As + issue * 512 + lane * 8) = *(const bf16x8_t*)ga;
            *(bf16x8_t*)(Bs + issue * 512 + lane * 8) = *(const bf16x8_t*)gb;
#endif
        }
        __syncthreads();

        bf16x8_t af[4][2], bfm[4][2];
        const char* Ab = (const char*)As;
        const char* Bb = (const char*)Bs;
        #pragma unroll
        for (int m = 0; m < 4; ++m) {
            int row = wr * 64 + m * 16 + lrow;
            #pragma unroll
            for (int ks = 0; ks < 2; ++ks) {
                int off = row * 128 + (((ks * 4 + lhi) ^ (lrow & 7)) * 16);
                af[m][ks] = *(const bf16x8_t*)(Ab + off);
            }
        }
        #pragma unroll
        for (int n = 0; n < 4; ++n) {
            int row = wc * 64 + n * 16 + lrow;
            #pragma unroll
            for (int ks = 0; ks < 2; ++ks) {
                int off = row * 128 + (((ks * 4 + lhi) ^ (lrow & 7)) * 16);
                bfm[n][ks] = *(const bf16x8_t*)(Bb + off);
            }
        }
        #pragma unroll
        for (int m = 0; m < 4; ++m)
            #pragma unroll
            for (int n = 0; n < 4; ++n)
                #pragma unroll
                for (int ks = 0; ks < 2; ++ks)
                    acc[m][n] = __builtin_amdgcn_mfma_f32_16x16x32_bf16(
                        af[m][ks], bfm[n][ks], acc[m][n], 0, 0, 0);
        __syncthreads();
    }

    #pragma unroll
    for (int m = 0; m < 4; ++m) {
        int row = m0 + wr * 64 + m * 16 + lhi * 4;
        #pragma unroll
        for (int n = 0; n < 4; ++n) {
            int col = n0 + wc * 64 + n * 16 + lrow;
            if (col < VOCAB) {
                float bo = bout[col];
                #pragma unroll
                for (int q = 0; q < 4; ++q)
                    out[(size_t)(row + q) * VOCAB + col] = tanhf(acc[m][n][q] + bo);
            }
        }
    }
}

// ---------------------------------------------------------------------------
extern "C" void kernel_launch(void* const* d_in, const int* in_sizes, int n_in,
                              void* d_out, int out_size, void* d_ws, size_t ws_size,
                              hipStream_t stream)
{
    const int*   inputs = (const int*)  d_in[0];
    const float* hidden = (const float*)d_in[1];
    const float* emb    = (const float*)d_in[2];
    const float* Wr     = (const float*)d_in[3];
    const float* br     = (const float*)d_in[4];
    const float* Wz     = (const float*)d_in[5];
    const float* bz     = (const float*)d_in[6];
    const float* Wg     = (const float*)d_in[7];
    const float* bg     = (const float*)d_in[8];
    const float* Wout   = (const float*)d_in[9];
    const float* bout   = (const float*)d_in[10];
    float* out = (float*)d_out;

    const size_t BH = BATCH * HID;                 // 131072

    float* ws = (float*)d_ws;
    float* h0      = ws;                           // BH
    float* h1      = h0 + BH;                      // BH
    float* rmat0   = h1 + BH;                      // BH
    float* rmat1   = rmat0 + BH;                   // BH
    float* part_rz = rmat1 + BH;                   // 2*8*262144
    float* part_g  = part_rz + 2 * NSPLIT * (BATCH * 2 * HID);  // 2*8*131072
    float* xemb    = part_g + 2 * NSPLIT * (BATCH * HID);       // T*B*H
    ushort_t* h1bf = (ushort_t*)(xemb + (size_t)T_STEPS * BH);  // T*B*H bf16
    ushort_t* WT   = h1bf + (size_t)T_STEPS * BH;               // VPAD*H bf16

    init_h<<<(int)(BH + 255) / 256, 256, 0, stream>>>(hidden, h0, h1);
    gather_kernel<<<T_STEPS * BATCH, 256, 0, stream>>>(inputs, emb, xemb);
    woutT_kernel<<<dim3(VPAD / 32, HID / 32), 256, 0, stream>>>(Wout, WT);

    for (int s = 0; s <= T_STEPS; ++s) {
        int do0 = (s < T_STEPS) ? 1 : 0;
        int do1 = (s >= 1) ? 1 : 0;
        const float* xemb_t0 = xemb + (size_t)s * BH;
        agemm_kernel<<<dim3(32, NSPLIT, 2), 256, 0, stream>>>(
            xemb_t0, h0, h1, Wr, Wz, part_rz, do0, do1);
        aact_kernel<<<dim3(128, 2), 256, 0, stream>>>(
            part_rz, br, rmat0, rmat1, do0, do1);
        bgemm_kernel<<<dim3(32, NSPLIT, 2), 256, 0, stream>>>(
            xemb_t0, h0, h1, rmat0, rmat1, Wg, part_g, do0, do1);
        bact_kernel<<<dim3(128, 2), 256, 0, stream>>>(
            part_rz, part_g, bz, bg, h0, h1, h1bf, s - 1, do0, do1);
    }

    final_h<<<(int)(BH + 255) / 256, 256, 0, stream>>>(
        h0, h1, out + (size_t)T_STEPS * BATCH * VOCAB);

    logits_mfma_kernel<<<dim3(VPAD / 128, 8192 / 128), 256, 0, stream>>>(
        h1bf, WT, bout, out);
}